// Round 6
// baseline (146.607 us; speedup 1.0000x reference)
//
#include <hip/hip_runtime.h>
#include <math.h>

#define ALPHA 0.3f
#define KMAX 8
#define KDIM 17
#define TWO_PI 6.28318530717958647692f

// half k-space as (kx,ky) columns: 136 cols kx<0 (full kz), 8 cols kx=0,ky<0
// (full kz), 1 special col (0,0) with kz in [-8,-1] only.
#define NCOL 145
#define NS (NCOL*17)      // 2465 S-entries per component

// -(alpha / sqrt(pi))
#define SELF_COEF (-0.16925687506432687f)
// 1/(4*alpha^2)
#define INV_4A2 (1.0f/(4.0f*ALPHA*ALPHA))
// erfc constants with alpha folded in
#define C1A (0.3275911f*ALPHA)
#define NA2 (-(ALPHA*ALPHA))

#define ITILE 256
#define JTILE 32
#define RCHUNK 32          // atoms per recip block
#define RBLK 192           // 3 waves; 145 active columns

__device__ __forceinline__ void invert3x3(const float* __restrict__ c, float inv[9], float* det_out) {
    float a00=c[0],a01=c[1],a02=c[2];
    float a10=c[3],a11=c[4],a12=c[5];
    float a20=c[6],a21=c[7],a22=c[8];
    float c00 =  a11*a22 - a12*a21;
    float c01 = -(a10*a22 - a12*a20);
    float c02 =  a10*a21 - a11*a20;
    float det = a00*c00 + a01*c01 + a02*c02;
    float id = 1.0f/det;
    inv[0] =  c00*id;
    inv[1] = -(a01*a22 - a02*a21)*id;
    inv[2] =  (a01*a12 - a02*a11)*id;
    inv[3] =  c01*id;
    inv[4] =  (a00*a22 - a02*a20)*id;
    inv[5] = -(a00*a12 - a02*a10)*id;
    inv[6] =  c02*id;
    inv[7] = -(a00*a21 - a01*a20)*id;
    inv[8] =  (a00*a11 - a01*a10)*id;
    *det_out = det;
}

__device__ __forceinline__ void col_to_k(int col, float* kx, float* ky) {
    if (col < 136)      { *kx = (float)(col/17 - 8); *ky = (float)(col%17 - 8); }
    else if (col < 144) { *kx = 0.f;                 *ky = (float)(col - 144);  }
    else                { *kx = 0.f;                 *ky = 0.f; }
}

// erfc(alpha*r) via A&S 7.1.26 with alpha pre-folded; |err| <= 1.5e-7.
__device__ __forceinline__ float erfc_a(float r, float r2) {
    float t = __builtin_amdgcn_rcpf(fmaf(C1A, r, 1.0f));
    float p = t * fmaf(t, fmaf(t, fmaf(t, fmaf(t, 1.061405429f, -1.453152027f),
                       1.421413741f), -0.284496736f), 0.254829592f);
    return p * __expf(NA2 * r2);
}

// block-wide sum; valid in thread 0. blockDim.x multiple of 64, <=256.
__device__ __forceinline__ float block_reduce(float v) {
    for (int o = 32; o > 0; o >>= 1) v += __shfl_down(v, o, 64);
    __shared__ float smem[4];
    int lane = threadIdx.x & 63, wid = threadIdx.x >> 6;
    if (lane == 0) smem[wid] = v;
    __syncthreads();
    int nw = (blockDim.x + 63) >> 6;
    v = ((int)threadIdx.x < nw) ? smem[threadIdx.x] : 0.0f;
    if (wid == 0) {
        for (int o = 4; o > 0; o >>= 1) v += __shfl_down(v, o, 64);
    }
    return v;
}

// Real space, triangular (j<i): 256 i x 32 j tiles; atomicAdd block sums to ws_e.
// Cutoff dropped: alpha*rc=3.0, tail contribution ~1e-2, 300x below threshold.
__global__ __launch_bounds__(256) void real_kernel(const float* __restrict__ pos,
                                                   const float* __restrict__ q,
                                                   const float* __restrict__ cell,
                                                   float* __restrict__ ws_e,
                                                   int N) {
    __shared__ float4 tile[JTILE];
    float inv[9]; float det;
    invert3x3(cell, inv, &det);
    bool ortho = (cell[1]==0.f) & (cell[2]==0.f) & (cell[3]==0.f) &
                 (cell[5]==0.f) & (cell[6]==0.f) & (cell[7]==0.f);

    int tid = threadIdx.x;
    int rbid = blockIdx.x;
    // invert rbid -> (bi, bj)
    int bi = 0, acc = 0;
    for (;;) {
        int up = min(N, (bi + 1) * ITILE);
        int nc = (up + JTILE - 1) / JTILE;
        if (rbid < acc + nc) break;
        acc += nc; ++bi;
    }
    int bj = rbid - acc;

    float c0 = cell[0], c4 = cell[4], c8 = cell[8];
    float c1 = cell[1], c2 = cell[2], c3 = cell[3];
    float c5 = cell[5], c6 = cell[6], c7 = cell[7];

    int ibase = bi * ITILE;
    int i = ibase + tid;
    bool ivalid = (i < N);
    float xi = 0.f, yi = 0.f, zi = 0.f, qi = 0.f;
    if (ivalid) { xi = pos[3*i]; yi = pos[3*i+1]; zi = pos[3*i+2]; qi = q[i]; }

    int jbase = bj * JTILE;
    int jcount = min(JTILE, N - jbase);
    if (tid < jcount) {
        int j = jbase + tid;
        tile[tid] = make_float4(pos[3*j], pos[3*j+1], pos[3*j+2], q[j]);
    }
    __syncthreads();

    bool full = (jbase + JTILE <= ibase) && (ibase + ITILE <= N) && (jcount == JTILE);

    float acc_e = 0.0f;
    if (ortho) {
        float i0 = inv[0], i4 = inv[4], i8 = inv[8];
        if (full) {
            #pragma unroll 8
            for (int t = 0; t < JTILE; ++t) {
                float4 p = tile[t];
                float dx = xi - p.x, dy = yi - p.y, dz = zi - p.z;
                float rx = fmaf(-c0, rintf(dx * i0), dx);
                float ry = fmaf(-c4, rintf(dy * i4), dy);
                float rz = fmaf(-c8, rintf(dz * i8), dz);
                float r2 = fmaf(rx, rx, fmaf(ry, ry, rz * rz));
                float rinv = __builtin_amdgcn_rsqf(r2);
                float r = r2 * rinv;
                acc_e = fmaf(p.w * rinv, erfc_a(r, r2), acc_e);
            }
        } else {
            #pragma unroll 8
            for (int t = 0; t < jcount; ++t) {
                float4 p = tile[t];
                float dx = xi - p.x, dy = yi - p.y, dz = zi - p.z;
                float rx = fmaf(-c0, rintf(dx * i0), dx);
                float ry = fmaf(-c4, rintf(dy * i4), dy);
                float rz = fmaf(-c8, rintf(dz * i8), dz);
                float r2 = fmaf(rx, rx, fmaf(ry, ry, rz * rz));
                float rinv = __builtin_amdgcn_rsqf(r2);
                float r = r2 * rinv;
                float val = p.w * rinv * erfc_a(r, r2);
                bool ok = ivalid && ((jbase + t) < i);
                acc_e += ok ? val : 0.0f;
            }
        }
    } else {
        #pragma unroll 4
        for (int t = 0; t < jcount; ++t) {
            float4 p = tile[t];
            float dx = xi - p.x, dy = yi - p.y, dz = zi - p.z;
            float fx = dx*inv[0] + dy*inv[3] + dz*inv[6];
            float fy = dx*inv[1] + dy*inv[4] + dz*inv[7];
            float fz = dx*inv[2] + dy*inv[5] + dz*inv[8];
            fx -= rintf(fx); fy -= rintf(fy); fz -= rintf(fz);
            float rx = fx*c0 + fy*c3 + fz*c6;
            float ry = fx*c1 + fy*c4 + fz*c7;
            float rz = fx*c2 + fy*c5 + fz*c8;
            float r2 = fmaf(rx, rx, fmaf(ry, ry, rz * rz));
            float rinv = __builtin_amdgcn_rsqf(r2);
            float r = r2 * rinv;
            float val = p.w * rinv * erfc_a(r, r2);
            bool ok = ivalid && ((jbase + t) < i);
            acc_e += ok ? val : 0.0f;
        }
    }
    acc_e *= qi;

    float s = block_reduce(acc_e);
    if (tid == 0) atomicAdd(ws_e, s);
}

// Reciprocal via kz-rotor recursion. Thread = (kx,ky) column; 17 kz accumulators
// in registers advanced by one complex multiply per step — inner loop has NO
// transcendentals (2 sincos per atom per thread, amortized over 17 k-points).
__global__ __launch_bounds__(RBLK) void recip_kernel(const float* __restrict__ pos,
                                                     const float* __restrict__ q,
                                                     const float* __restrict__ cell,
                                                     float* __restrict__ s_re,
                                                     float* __restrict__ s_im,
                                                     int N) {
    // per-atom staging: wx, wy, q*bz (rotor^-8), cz (rotor e^{i2pi wz})
    __shared__ float tw[RCHUNK][6];
    float inv[9]; float det;
    invert3x3(cell, inv, &det);
    bool ortho = (cell[1]==0.f) & (cell[2]==0.f) & (cell[3]==0.f) &
                 (cell[5]==0.f) & (cell[6]==0.f) & (cell[7]==0.f);

    int tid = threadIdx.x;
    int a0 = blockIdx.x * RCHUNK;
    int cnt = min(RCHUNK, N - a0);

    if (tid < cnt) {
        int a = a0 + tid;
        float x = pos[3*a], y = pos[3*a+1], z = pos[3*a+2];
        float wx, wy, wz;
        if (ortho) { wx = x*inv[0]; wy = y*inv[4]; wz = z*inv[8]; }
        else {
            wx = inv[0]*x + inv[3]*y + inv[6]*z;
            wy = inv[1]*x + inv[4]*y + inv[7]*z;
            wz = inv[2]*x + inv[5]*y + inv[8]*z;
        }
        float qa = q[a];
        float rz = wz - rintf(wz);
        float czr = __builtin_amdgcn_cosf(rz);
        float czi = __builtin_amdgcn_sinf(rz);
        float u = -8.0f * wz;
        u -= rintf(u);
        float bzr = qa * __builtin_amdgcn_cosf(u);
        float bzi = qa * __builtin_amdgcn_sinf(u);
        tw[tid][0] = wx;  tw[tid][1] = wy;
        tw[tid][2] = bzr; tw[tid][3] = bzi;
        tw[tid][4] = czr; tw[tid][5] = czi;
    }
    __syncthreads();

    int col = tid;
    float kx, ky;
    col_to_k(col < NCOL ? col : 0, &kx, &ky);

    float ar[17], ai[17];
    #pragma unroll
    for (int u = 0; u < 17; ++u) { ar[u] = 0.f; ai[u] = 0.f; }

    for (int t = 0; t < cnt; ++t) {
        float wx  = tw[t][0], wy  = tw[t][1];
        float bzr = tw[t][2], bzi = tw[t][3];
        float czr = tw[t][4], czi = tw[t][5];
        float ph = fmaf(kx, wx, ky * wy);
        ph -= rintf(ph);
        float cr = __builtin_amdgcn_cosf(ph);
        float ci = __builtin_amdgcn_sinf(ph);
        // z = q * e^{i2pi(kx wx + ky wy)} * e^{-i2pi*8*wz}
        float zr = fmaf(cr, bzr, -ci * bzi);
        float zi = fmaf(cr, bzi,  ci * bzr);
        #pragma unroll
        for (int u = 0; u < 17; ++u) {
            ar[u] += zr; ai[u] += zi;
            float nzr = fmaf(zr, czr, -zi * czi);
            float nzi = fmaf(zr, czi,  zi * czr);
            zr = nzr; zi = nzi;
        }
    }

    if (col < NCOL) {
        int lim = (col == NCOL-1) ? 8 : 17;   // special (0,0) column: kz<0 only
        for (int u = 0; u < lim; ++u) {
            atomicAdd(&s_re[col*17 + u], ar[u]);
            atomicAdd(&s_im[col*17 + u], ai[u]);
        }
    }
}

// Single-block finalize: k-space energy from S, self-energy, + real partial.
__global__ __launch_bounds__(256) void finalize_kernel(const float* __restrict__ s_re,
                                                       const float* __restrict__ s_im,
                                                       const float* __restrict__ ws_e,
                                                       const float* __restrict__ q,
                                                       const float* __restrict__ cell,
                                                       float* __restrict__ e_out,
                                                       int N) {
    float inv[9]; float det;
    invert3x3(cell, inv, &det);
    float vol = fabsf(det);
    float pref = 2.0f * (TWO_PI / vol);   // x2: +-k symmetry
    int tid = threadIdx.x;

    float acc = 0.0f;
    for (int idx = tid; idx < NS; idx += 256) {
        int col = idx / 17;
        int u   = idx % 17;
        if (col == NCOL-1 && u >= 8) continue;   // untouched (incl. k=0)
        float kx, ky;
        col_to_k(col, &kx, &ky);
        float kz = (float)(u - 8);
        float kvx = TWO_PI * (kx*inv[0] + ky*inv[1] + kz*inv[2]);
        float kvy = TWO_PI * (kx*inv[3] + ky*inv[4] + kz*inv[5]);
        float kvz = TWO_PI * (kx*inv[6] + ky*inv[7] + kz*inv[8]);
        float k2 = fmaf(kvx, kvx, fmaf(kvy, kvy, kvz * kvz));
        float coeff = __expf(-k2 * INV_4A2) / k2;
        float sr = s_re[idx], si = s_im[idx];
        acc = fmaf(pref * coeff, fmaf(sr, sr, si * si), acc);
    }
    for (int t = tid; t < N; t += 256) {
        float qt = q[t];
        acc = fmaf(SELF_COEF * qt, qt, acc);
    }
    if (tid == 0) acc += ws_e[0];
    float s = block_reduce(acc);
    if (tid == 0) e_out[0] = s;
}

extern "C" void kernel_launch(void* const* d_in, const int* in_sizes, int n_in,
                              void* d_out, int out_size, void* d_ws, size_t ws_size,
                              hipStream_t stream) {
    const float* pos  = (const float*)d_in[0];
    const float* q    = (const float*)d_in[1];
    const float* cell = (const float*)d_in[2];
    int N = in_sizes[1];
    float* e_out = (float*)d_out;

    float* s_re = (float*)d_ws;        // NS floats
    float* s_im = s_re + NS;           // NS floats
    float* ws_e = s_im + NS;           // 1 float

    hipMemsetAsync(s_re, 0, (2*NS + 1) * sizeof(float), stream);

    // real-space triangular block count
    int nbi = (N + ITILE - 1) / ITILE;
    int nb_real = 0;
    for (int bi = 0; bi < nbi; ++bi) {
        int up = (N < (bi + 1) * ITILE) ? N : (bi + 1) * ITILE;
        nb_real += (up + JTILE - 1) / JTILE;
    }

    real_kernel<<<nb_real, 256, 0, stream>>>(pos, q, cell, ws_e, N);

    int nb_recip = (N + RCHUNK - 1) / RCHUNK;
    recip_kernel<<<nb_recip, RBLK, 0, stream>>>(pos, q, cell, s_re, s_im, N);

    finalize_kernel<<<1, 256, 0, stream>>>(s_re, s_im, ws_e, q, cell, e_out, N);
}

// Round 7
// 87.302 us; speedup vs baseline: 1.6793x; 1.6793x over previous
//
#include <hip/hip_runtime.h>
#include <math.h>

#define ALPHA 0.3f
#define KMAX 8
#define KDIM 17
#define KD2 (KDIM*KDIM)                 // 289
#define NK_FULL (KDIM*KDIM*KDIM - 1)    // 4912
#define NK_HALF (NK_FULL/2)             // 2456 (half k-space: flat idx < center)
#define RECIP_KB ((NK_HALF + 255)/256)  // 10
#define KPAD (RECIP_KB*256)             // 2560
#define RECIP_CHUNKS 16
#define TWO_PI 6.28318530717958647692f

// -(alpha / sqrt(pi))
#define SELF_COEF (-0.16925687506432687f)
// 1/(4*alpha^2)
#define INV_4A2 (1.0f/(4.0f*ALPHA*ALPHA))
// erfc constants with alpha folded in
#define C1A (0.3275911f*ALPHA)
#define NA2 (-(ALPHA*ALPHA))

#define ITILE 256
#define JTILE 32

__device__ __forceinline__ void invert3x3(const float* __restrict__ c, float inv[9], float* det_out) {
    float a00=c[0],a01=c[1],a02=c[2];
    float a10=c[3],a11=c[4],a12=c[5];
    float a20=c[6],a21=c[7],a22=c[8];
    float c00 =  a11*a22 - a12*a21;
    float c01 = -(a10*a22 - a12*a20);
    float c02 =  a10*a21 - a11*a20;
    float det = a00*c00 + a01*c01 + a02*c02;
    float id = 1.0f/det;
    inv[0] =  c00*id;
    inv[1] = -(a01*a22 - a02*a21)*id;
    inv[2] =  (a01*a12 - a02*a11)*id;
    inv[3] =  c01*id;
    inv[4] =  (a00*a22 - a02*a20)*id;
    inv[5] = -(a00*a12 - a02*a10)*id;
    inv[6] =  c02*id;
    inv[7] = -(a00*a21 - a01*a20)*id;
    inv[8] =  (a00*a11 - a01*a10)*id;
    *det_out = det;
}

// erfc(alpha*r) via A&S 7.1.26 with alpha pre-folded; |err| <= 1.5e-7.
__device__ __forceinline__ float erfc_a(float r, float r2) {
    float t = __builtin_amdgcn_rcpf(fmaf(C1A, r, 1.0f));
    float p = t * fmaf(t, fmaf(t, fmaf(t, fmaf(t, 1.061405429f, -1.453152027f),
                       1.421413741f), -0.284496736f), 0.254829592f);
    return p * __expf(NA2 * r2);
}

// block-wide sum; valid in thread 0. blockDim.x multiple of 64, <=256.
__device__ __forceinline__ float block_reduce(float v) {
    for (int o = 32; o > 0; o >>= 1) v += __shfl_down(v, o, 64);
    __shared__ float smem[4];
    int lane = threadIdx.x & 63, wid = threadIdx.x >> 6;
    if (lane == 0) smem[wid] = v;
    __syncthreads();
    int nw = (blockDim.x + 63) >> 6;
    v = ((int)threadIdx.x < nw) ? smem[threadIdx.x] : 0.0f;
    if (wid == 0) {
        for (int o = 4; o > 0; o >>= 1) v += __shfl_down(v, o, 64);
    }
    return v;
}

// Real space, triangular (j<i): 256 i x 32 j tiles; block partial -> rpart[rbid]
// (plain store, no atomics/memset). Cutoff dropped: alpha*rc=3.0, tail ~1e-2,
// 300x below the 3.36 threshold.
__global__ __launch_bounds__(256) void real_kernel(const float* __restrict__ pos,
                                                   const float* __restrict__ q,
                                                   const float* __restrict__ cell,
                                                   float* __restrict__ rpart,
                                                   int N) {
    __shared__ float4 tile[JTILE];
    float inv[9]; float det;
    invert3x3(cell, inv, &det);
    bool ortho = (cell[1]==0.f) & (cell[2]==0.f) & (cell[3]==0.f) &
                 (cell[5]==0.f) & (cell[6]==0.f) & (cell[7]==0.f);

    int tid = threadIdx.x;
    int rbid = blockIdx.x;
    // invert rbid -> (bi, bj)
    int bi = 0, acc = 0;
    for (;;) {
        int up = min(N, (bi + 1) * ITILE);
        int nc = (up + JTILE - 1) / JTILE;
        if (rbid < acc + nc) break;
        acc += nc; ++bi;
    }
    int bj = rbid - acc;

    float c0 = cell[0], c4 = cell[4], c8 = cell[8];
    float c1 = cell[1], c2 = cell[2], c3 = cell[3];
    float c5 = cell[5], c6 = cell[6], c7 = cell[7];

    int ibase = bi * ITILE;
    int i = ibase + tid;
    bool ivalid = (i < N);
    float xi = 0.f, yi = 0.f, zi = 0.f, qi = 0.f;
    if (ivalid) { xi = pos[3*i]; yi = pos[3*i+1]; zi = pos[3*i+2]; qi = q[i]; }

    int jbase = bj * JTILE;
    int jcount = min(JTILE, N - jbase);
    if (tid < jcount) {
        int j = jbase + tid;
        tile[tid] = make_float4(pos[3*j], pos[3*j+1], pos[3*j+2], q[j]);
    }
    __syncthreads();

    bool full = (jbase + JTILE <= ibase) && (ibase + ITILE <= N) && (jcount == JTILE);

    float acc0 = 0.0f, acc1 = 0.0f;   // dual accumulators for ILP
    if (ortho) {
        float i0 = inv[0], i4 = inv[4], i8 = inv[8];
        if (full) {
            #pragma unroll
            for (int t = 0; t < JTILE; t += 2) {
                float4 p = tile[t];
                float4 p2 = tile[t+1];
                float dx = xi - p.x, dy = yi - p.y, dz = zi - p.z;
                float ex = xi - p2.x, ey = yi - p2.y, ez = zi - p2.z;
                float rx = fmaf(-c0, rintf(dx * i0), dx);
                float ry = fmaf(-c4, rintf(dy * i4), dy);
                float rz = fmaf(-c8, rintf(dz * i8), dz);
                float sx = fmaf(-c0, rintf(ex * i0), ex);
                float sy = fmaf(-c4, rintf(ey * i4), ey);
                float sz = fmaf(-c8, rintf(ez * i8), ez);
                float r2a = fmaf(rx, rx, fmaf(ry, ry, rz * rz));
                float r2b = fmaf(sx, sx, fmaf(sy, sy, sz * sz));
                float ria = __builtin_amdgcn_rsqf(r2a);
                float rib = __builtin_amdgcn_rsqf(r2b);
                acc0 = fmaf(p.w  * ria, erfc_a(r2a * ria, r2a), acc0);
                acc1 = fmaf(p2.w * rib, erfc_a(r2b * rib, r2b), acc1);
            }
        } else {
            #pragma unroll 4
            for (int t = 0; t < jcount; ++t) {
                float4 p = tile[t];
                float dx = xi - p.x, dy = yi - p.y, dz = zi - p.z;
                float rx = fmaf(-c0, rintf(dx * i0), dx);
                float ry = fmaf(-c4, rintf(dy * i4), dy);
                float rz = fmaf(-c8, rintf(dz * i8), dz);
                float r2 = fmaf(rx, rx, fmaf(ry, ry, rz * rz));
                float rinv = __builtin_amdgcn_rsqf(r2);
                float val = p.w * rinv * erfc_a(r2 * rinv, r2);
                bool ok = ivalid && ((jbase + t) < i);
                acc0 += ok ? val : 0.0f;
            }
        }
    } else {
        #pragma unroll 4
        for (int t = 0; t < jcount; ++t) {
            float4 p = tile[t];
            float dx = xi - p.x, dy = yi - p.y, dz = zi - p.z;
            float fx = dx*inv[0] + dy*inv[3] + dz*inv[6];
            float fy = dx*inv[1] + dy*inv[4] + dz*inv[7];
            float fz = dx*inv[2] + dy*inv[5] + dz*inv[8];
            fx -= rintf(fx); fy -= rintf(fy); fz -= rintf(fz);
            float rx = fx*c0 + fy*c3 + fz*c6;
            float ry = fx*c1 + fy*c4 + fz*c7;
            float rz = fx*c2 + fy*c5 + fz*c8;
            float r2 = fmaf(rx, rx, fmaf(ry, ry, rz * rz));
            float rinv = __builtin_amdgcn_rsqf(r2);
            float val = p.w * rinv * erfc_a(r2 * rinv, r2);
            bool ok = ivalid && ((jbase + t) < i);
            acc0 += ok ? val : 0.0f;
        }
    }
    float acc_e = (acc0 + acc1) * qi;

    float s = block_reduce(acc_e);
    if (tid == 0) rpart[rbid] = s;
}

// Reciprocal: direct sincos over half k-space, per-(kblock,chunk) partials into
// spart slices (no atomics, no pre-zero). Known-good R4/R5 form.
__global__ __launch_bounds__(256) void recip_kernel(const float* __restrict__ pos,
                                                    const float* __restrict__ q,
                                                    const float* __restrict__ cell,
                                                    float* __restrict__ spart,
                                                    int N) {
    __shared__ float4 tile[256];
    float inv[9]; float det;
    invert3x3(cell, inv, &det);
    bool ortho = (cell[1]==0.f) & (cell[2]==0.f) & (cell[3]==0.f) &
                 (cell[5]==0.f) & (cell[6]==0.f) & (cell[7]==0.f);

    int tid = threadIdx.x;
    int kb    = blockIdx.x % RECIP_KB;
    int chunk = blockIdx.x / RECIP_KB;
    int k = kb * 256 + tid;                 // [0, KPAD)
    bool kvalid = (k < NK_HALF);
    int kk = kvalid ? k : 0;
    float kx = (float)(kk / KD2 - KMAX);
    float ky = (float)((kk / KDIM) % KDIM - KMAX);
    float kz = (float)(kk % KDIM - KMAX);

    int per = (N + RECIP_CHUNKS - 1) / RECIP_CHUNKS;
    int a0 = chunk * per;
    int a1 = min(N, a0 + per);

    float sre = 0.0f, sim = 0.0f;
    for (int base = a0; base < a1; base += 256) {
        int cnt = min(256, a1 - base);
        __syncthreads();
        if (tid < cnt) {
            int a = base + tid;
            float x = pos[3*a], y = pos[3*a+1], z = pos[3*a+2];
            float wx, wy, wz;
            if (ortho) { wx = x*inv[0]; wy = y*inv[4]; wz = z*inv[8]; }
            else {
                wx = inv[0]*x + inv[3]*y + inv[6]*z;
                wy = inv[1]*x + inv[4]*y + inv[7]*z;
                wz = inv[2]*x + inv[5]*y + inv[8]*z;
            }
            tile[tid] = make_float4(wx, wy, wz, q[a]);
        }
        __syncthreads();
        #pragma unroll 4
        for (int t = 0; t < cnt; ++t) {
            float4 w = tile[t];
            // phase in revolutions; v_sin/v_cos take revolutions directly
            float ph = fmaf(kx, w.x, fmaf(ky, w.y, kz * w.z));
            ph -= rintf(ph);                 // exact reduction to [-0.5, 0.5]
            sre = fmaf(w.w, __builtin_amdgcn_cosf(ph), sre);
            sim = fmaf(w.w, __builtin_amdgcn_sinf(ph), sim);
        }
    }
    spart[(size_t)(chunk*2    ) * KPAD + k] = kvalid ? sre : 0.0f;
    spart[(size_t)(chunk*2 + 1) * KPAD + k] = kvalid ? sim : 0.0f;
}

// Single-block finalize: chunk partials -> |S(k)|^2 (x2 for +-k) with coeff,
// plus self-energy, plus real-space block partials. Plain store to e_out.
__global__ __launch_bounds__(256) void finalize_kernel(const float* __restrict__ spart,
                                                       const float* __restrict__ rpart,
                                                       const float* __restrict__ q,
                                                       const float* __restrict__ cell,
                                                       float* __restrict__ e_out,
                                                       int N, int nb_real) {
    float inv[9]; float det;
    invert3x3(cell, inv, &det);
    float vol = fabsf(det);
    float pref = 2.0f * (TWO_PI / vol);   // x2: +-k symmetry
    int tid = threadIdx.x;

    float acc = 0.0f;
    for (int t = tid; t < NK_HALF; t += 256) {
        float sr = 0.0f, si = 0.0f;
        #pragma unroll
        for (int c = 0; c < RECIP_CHUNKS; ++c) {
            sr += spart[(size_t)(c*2    ) * KPAD + t];
            si += spart[(size_t)(c*2 + 1) * KPAD + t];
        }
        float nx = (float)(t / KD2 - KMAX);
        float ny = (float)((t / KDIM) % KDIM - KMAX);
        float nz = (float)(t % KDIM - KMAX);
        float kvx = TWO_PI * (nx*inv[0] + ny*inv[1] + nz*inv[2]);
        float kvy = TWO_PI * (nx*inv[3] + ny*inv[4] + nz*inv[5]);
        float kvz = TWO_PI * (nx*inv[6] + ny*inv[7] + nz*inv[8]);
        float k2 = fmaf(kvx, kvx, fmaf(kvy, kvy, kvz * kvz));
        float coeff = __expf(-k2 * INV_4A2) / k2;
        acc = fmaf(pref * coeff, fmaf(sr, sr, si * si), acc);
    }
    for (int t = tid; t < N; t += 256) {
        float qt = q[t];
        acc = fmaf(SELF_COEF * qt, qt, acc);
    }
    for (int t = tid; t < nb_real; t += 256) {
        acc += rpart[t];
    }
    float s = block_reduce(acc);
    if (tid == 0) e_out[0] = s;
}

extern "C" void kernel_launch(void* const* d_in, const int* in_sizes, int n_in,
                              void* d_out, int out_size, void* d_ws, size_t ws_size,
                              hipStream_t stream) {
    const float* pos  = (const float*)d_in[0];
    const float* q    = (const float*)d_in[1];
    const float* cell = (const float*)d_in[2];
    int N = in_sizes[1];
    float* e_out = (float*)d_out;

    float* spart = (float*)d_ws;                          // RECIP_CHUNKS*2*KPAD floats
    float* rpart = spart + (size_t)RECIP_CHUNKS*2*KPAD;   // nb_real floats

    // real-space triangular block count
    int nbi = (N + ITILE - 1) / ITILE;
    int nb_real = 0;
    for (int bi = 0; bi < nbi; ++bi) {
        int up = (N < (bi + 1) * ITILE) ? N : (bi + 1) * ITILE;
        nb_real += (up + JTILE - 1) / JTILE;
    }

    real_kernel<<<nb_real, 256, 0, stream>>>(pos, q, cell, rpart, N);

    recip_kernel<<<RECIP_KB * RECIP_CHUNKS, 256, 0, stream>>>(pos, q, cell, spart, N);

    finalize_kernel<<<1, 256, 0, stream>>>(spart, rpart, q, cell, e_out, N, nb_real);
}

// Round 8
// 80.714 us; speedup vs baseline: 1.8164x; 1.0816x over previous
//
#include <hip/hip_runtime.h>
#include <math.h>

#define ALPHA 0.3f
#define KMAX 8
#define KDIM 17
#define KD2 (KDIM*KDIM)                 // 289
#define NK_FULL (KDIM*KDIM*KDIM - 1)    // 4912
#define NK_HALF (NK_FULL/2)             // 2456 (half k-space: flat idx < center)
#define RECIP_KB ((NK_HALF + 255)/256)  // 10
#define KPAD (RECIP_KB*256)             // 2560
#define RECIP_CHUNKS 16
#define TWO_PI 6.28318530717958647692f

// -(alpha / sqrt(pi))
#define SELF_COEF (-0.16925687506432687f)
// 1/(4*alpha^2)
#define INV_4A2 (1.0f/(4.0f*ALPHA*ALPHA))
// erfc constants with alpha folded in (physical-distance form)
#define C1A (0.3275911f*ALPHA)
#define NA2 (-(ALPHA*ALPHA))

#define ITILE 512     // i-atoms per real block (2 per thread)
#define JTILE 32      // j-atoms per real block

__device__ __forceinline__ void invert3x3(const float* __restrict__ c, float inv[9], float* det_out) {
    float a00=c[0],a01=c[1],a02=c[2];
    float a10=c[3],a11=c[4],a12=c[5];
    float a20=c[6],a21=c[7],a22=c[8];
    float c00 =  a11*a22 - a12*a21;
    float c01 = -(a10*a22 - a12*a20);
    float c02 =  a10*a21 - a11*a20;
    float det = a00*c00 + a01*c01 + a02*c02;
    float id = 1.0f/det;
    inv[0] =  c00*id;
    inv[1] = -(a01*a22 - a02*a21)*id;
    inv[2] =  (a01*a12 - a02*a11)*id;
    inv[3] =  c01*id;
    inv[4] =  (a00*a22 - a02*a20)*id;
    inv[5] = -(a00*a12 - a02*a10)*id;
    inv[6] =  c02*id;
    inv[7] = -(a00*a21 - a01*a20)*id;
    inv[8] =  (a00*a11 - a01*a10)*id;
    *det_out = det;
}

// erfc(alpha*r) via A&S 7.1.26 with alpha pre-folded; |err| <= 1.5e-7.
__device__ __forceinline__ float erfc_a(float r, float r2) {
    float t = __builtin_amdgcn_rcpf(fmaf(C1A, r, 1.0f));
    float p = t * fmaf(t, fmaf(t, fmaf(t, fmaf(t, 1.061405429f, -1.453152027f),
                       1.421413741f), -0.284496736f), 0.254829592f);
    return p * __expf(NA2 * r2);
}

// block-wide sum; valid in thread 0. blockDim.x multiple of 64, <=256.
__device__ __forceinline__ float block_reduce(float v) {
    for (int o = 32; o > 0; o >>= 1) v += __shfl_down(v, o, 64);
    __shared__ float smem[4];
    int lane = threadIdx.x & 63, wid = threadIdx.x >> 6;
    if (lane == 0) smem[wid] = v;
    __syncthreads();
    int nw = (blockDim.x + 63) >> 6;
    v = ((int)threadIdx.x < nw) ? smem[threadIdx.x] : 0.0f;
    if (wid == 0) {
        for (int o = 4; o > 0; o >>= 1) v += __shfl_down(v, o, 64);
    }
    return v;
}

// Fused: blocks [0, nb_recip) = reciprocal S(k) partials (no atomics, no
// pre-zero); remaining blocks = triangular (j<i) real-space tiles, 512 i x 32 j,
// 2 i-atoms per thread, block partial -> rpart[rbid] (plain store).
// Cutoff dropped: alpha*rc=3.0, tail ~1e-2, 300x below the 3.36 threshold.
__global__ __launch_bounds__(256) void fused_kernel(const float* __restrict__ pos,
                                                    const float* __restrict__ q,
                                                    const float* __restrict__ cell,
                                                    float* __restrict__ spart,
                                                    float* __restrict__ rpart,
                                                    int N, int nb_recip) {
    float inv[9]; float det;
    invert3x3(cell, inv, &det);
    bool ortho = (cell[1]==0.f) & (cell[2]==0.f) & (cell[3]==0.f) &
                 (cell[5]==0.f) & (cell[6]==0.f) & (cell[7]==0.f);
    bool cubic = ortho & (cell[0]==cell[4]) & (cell[0]==cell[8]);

    int bid = blockIdx.x;
    int tid = threadIdx.x;

    if (bid < nb_recip) {
        // ---------- reciprocal: S(k) partials over half k-space ----------
        __shared__ float4 atile[256];
        int kb    = bid % RECIP_KB;
        int chunk = bid / RECIP_KB;
        int k = kb * 256 + tid;                 // [0, KPAD)
        bool kvalid = (k < NK_HALF);
        int kk = kvalid ? k : 0;
        float kx = (float)(kk / KD2 - KMAX);
        float ky = (float)((kk / KDIM) % KDIM - KMAX);
        float kz = (float)(kk % KDIM - KMAX);

        int per = (N + RECIP_CHUNKS - 1) / RECIP_CHUNKS;
        int a0 = chunk * per;
        int a1 = min(N, a0 + per);

        float sre = 0.0f, sim = 0.0f;
        for (int base = a0; base < a1; base += 256) {
            int cnt = min(256, a1 - base);
            __syncthreads();
            if (tid < cnt) {
                int a = base + tid;
                float x = pos[3*a], y = pos[3*a+1], z = pos[3*a+2];
                float wx, wy, wz;
                if (ortho) { wx = x*inv[0]; wy = y*inv[4]; wz = z*inv[8]; }
                else {
                    wx = inv[0]*x + inv[3]*y + inv[6]*z;
                    wy = inv[1]*x + inv[4]*y + inv[7]*z;
                    wz = inv[2]*x + inv[5]*y + inv[8]*z;
                }
                atile[tid] = make_float4(wx, wy, wz, q[a]);
            }
            __syncthreads();
            #pragma unroll 4
            for (int t = 0; t < cnt; ++t) {
                float4 w = atile[t];
                // phase in revolutions; v_sin/v_cos take revolutions directly
                float ph = fmaf(kx, w.x, fmaf(ky, w.y, kz * w.z));
                ph -= rintf(ph);                 // exact reduction to [-0.5, 0.5]
                sre = fmaf(w.w, __builtin_amdgcn_cosf(ph), sre);
                sim = fmaf(w.w, __builtin_amdgcn_sinf(ph), sim);
            }
        }
        spart[(size_t)(chunk*2    ) * KPAD + k] = kvalid ? sre : 0.0f;
        spart[(size_t)(chunk*2 + 1) * KPAD + k] = kvalid ? sim : 0.0f;
    } else {
        // ---------- real space, triangular, 2 i-atoms per thread ----------
        __shared__ float4 tile[JTILE];
        int rbid = bid - nb_recip;
        int bi = 0, acc = 0;
        for (;;) {
            int up = min(N, (bi + 1) * ITILE);
            int nc = (up + JTILE - 1) / JTILE;
            if (rbid < acc + nc) break;
            acc += nc; ++bi;
        }
        int bj = rbid - acc;

        int ibase = bi * ITILE;
        int jbase = bj * JTILE;
        int jcount = min(JTILE, N - jbase);

        int i1 = ibase + tid;
        int i2 = i1 + 256;
        bool v1 = (i1 < N), v2 = (i2 < N);

        float L = cell[0], invL = inv[0];
        // cubic-scaled erfc constants (runtime wave-uniform scalars)
        float C1AL = C1A * L;          // 0.3275911 * alpha * L
        float NBL  = NA2 * L * L;      // -(alpha*L)^2

        float x1=0.f,y1=0.f,z1=0.f,q1=0.f, x2=0.f,y2=0.f,z2=0.f,q2=0.f;

        if (cubic) {
            if (v1) { x1 = pos[3*i1]*invL; y1 = pos[3*i1+1]*invL; z1 = pos[3*i1+2]*invL; q1 = q[i1]; }
            if (v2) { x2 = pos[3*i2]*invL; y2 = pos[3*i2+1]*invL; z2 = pos[3*i2+2]*invL; q2 = q[i2]; }
            if (tid < jcount) {
                int j = jbase + tid;
                tile[tid] = make_float4(pos[3*j]*invL, pos[3*j+1]*invL, pos[3*j+2]*invL, q[j]);
            }
        } else {
            if (v1) { x1 = pos[3*i1]; y1 = pos[3*i1+1]; z1 = pos[3*i1+2]; q1 = q[i1]; }
            if (v2) { x2 = pos[3*i2]; y2 = pos[3*i2+1]; z2 = pos[3*i2+2]; q2 = q[i2]; }
            if (tid < jcount) {
                int j = jbase + tid;
                tile[tid] = make_float4(pos[3*j], pos[3*j+1], pos[3*j+2], q[j]);
            }
        }
        __syncthreads();

        bool full = (jbase + JTILE <= ibase) && (ibase + ITILE <= N) && (jcount == JTILE);

        float acc1 = 0.0f, acc2 = 0.0f;
        if (cubic) {
            if (full) {
                #pragma unroll 4
                for (int t = 0; t < JTILE; ++t) {
                    float4 p = tile[t];
                    // atom 1
                    float dx = x1 - p.x, dy = y1 - p.y, dz = z1 - p.z;
                    dx -= rintf(dx); dy -= rintf(dy); dz -= rintf(dz);
                    float f2a = fmaf(dx, dx, fmaf(dy, dy, dz * dz));
                    // atom 2
                    float ex = x2 - p.x, ey = y2 - p.y, ez = z2 - p.z;
                    ex -= rintf(ex); ey -= rintf(ey); ez -= rintf(ez);
                    float f2b = fmaf(ex, ex, fmaf(ey, ey, ez * ez));

                    float rsa = __builtin_amdgcn_rsqf(f2a);
                    float rsb = __builtin_amdgcn_rsqf(f2b);
                    float fma_ = f2a * rsa, fmb_ = f2b * rsb;   // |f|
                    float ta = __builtin_amdgcn_rcpf(fmaf(C1AL, fma_, 1.0f));
                    float tb = __builtin_amdgcn_rcpf(fmaf(C1AL, fmb_, 1.0f));
                    float pa = ta * fmaf(ta, fmaf(ta, fmaf(ta, fmaf(ta, 1.061405429f, -1.453152027f),
                                        1.421413741f), -0.284496736f), 0.254829592f);
                    float pb = tb * fmaf(tb, fmaf(tb, fmaf(tb, fmaf(tb, 1.061405429f, -1.453152027f),
                                        1.421413741f), -0.284496736f), 0.254829592f);
                    float ea = __expf(NBL * f2a);
                    float eb = __expf(NBL * f2b);
                    acc1 = fmaf(p.w * rsa * pa, ea, acc1);
                    acc2 = fmaf(p.w * rsb * pb, eb, acc2);
                }
            } else {
                #pragma unroll 4
                for (int t = 0; t < jcount; ++t) {
                    float4 p = tile[t];
                    int j = jbase + t;
                    float dx = x1 - p.x, dy = y1 - p.y, dz = z1 - p.z;
                    dx -= rintf(dx); dy -= rintf(dy); dz -= rintf(dz);
                    float f2a = fmaf(dx, dx, fmaf(dy, dy, dz * dz));
                    float ex = x2 - p.x, ey = y2 - p.y, ez = z2 - p.z;
                    ex -= rintf(ex); ey -= rintf(ey); ez -= rintf(ez);
                    float f2b = fmaf(ex, ex, fmaf(ey, ey, ez * ez));

                    float rsa = __builtin_amdgcn_rsqf(f2a);
                    float rsb = __builtin_amdgcn_rsqf(f2b);
                    float fma_ = f2a * rsa, fmb_ = f2b * rsb;
                    float ta = __builtin_amdgcn_rcpf(fmaf(C1AL, fma_, 1.0f));
                    float tb = __builtin_amdgcn_rcpf(fmaf(C1AL, fmb_, 1.0f));
                    float pa = ta * fmaf(ta, fmaf(ta, fmaf(ta, fmaf(ta, 1.061405429f, -1.453152027f),
                                        1.421413741f), -0.284496736f), 0.254829592f);
                    float pb = tb * fmaf(tb, fmaf(tb, fmaf(tb, fmaf(tb, 1.061405429f, -1.453152027f),
                                        1.421413741f), -0.284496736f), 0.254829592f);
                    float ea = __expf(NBL * f2a);
                    float eb = __expf(NBL * f2b);
                    float va = p.w * rsa * pa * ea;
                    float vb = p.w * rsb * pb * eb;
                    acc1 += (v1 && j < i1) ? va : 0.0f;
                    acc2 += (v2 && j < i2) ? vb : 0.0f;
                }
            }
            // fold 1/L (scaled-distance correction) with per-atom charge
            float acc_e = (acc1 * q1 + acc2 * q2) * invL;
            float s = block_reduce(acc_e);
            if (tid == 0) rpart[rbid] = s;
        } else {
            // general-cell fallback (also non-cubic ortho): inv-matrix min image
            float c0 = cell[0], c1 = cell[1], c2 = cell[2];
            float c3 = cell[3], c4 = cell[4], c5 = cell[5];
            float c6 = cell[6], c7 = cell[7], c8 = cell[8];
            #pragma unroll 2
            for (int t = 0; t < jcount; ++t) {
                float4 p = tile[t];
                int j = jbase + t;
                // atom 1
                {
                    float dx = x1 - p.x, dy = y1 - p.y, dz = z1 - p.z;
                    float fx = dx*inv[0] + dy*inv[3] + dz*inv[6];
                    float fy = dx*inv[1] + dy*inv[4] + dz*inv[7];
                    float fz = dx*inv[2] + dy*inv[5] + dz*inv[8];
                    fx -= rintf(fx); fy -= rintf(fy); fz -= rintf(fz);
                    float rx = fx*c0 + fy*c3 + fz*c6;
                    float ry = fx*c1 + fy*c4 + fz*c7;
                    float rz = fx*c2 + fy*c5 + fz*c8;
                    float r2 = fmaf(rx, rx, fmaf(ry, ry, rz * rz));
                    float rinv = __builtin_amdgcn_rsqf(r2);
                    float val = p.w * rinv * erfc_a(r2 * rinv, r2);
                    acc1 += (v1 && j < i1) ? val : 0.0f;
                }
                // atom 2
                {
                    float dx = x2 - p.x, dy = y2 - p.y, dz = z2 - p.z;
                    float fx = dx*inv[0] + dy*inv[3] + dz*inv[6];
                    float fy = dx*inv[1] + dy*inv[4] + dz*inv[7];
                    float fz = dx*inv[2] + dy*inv[5] + dz*inv[8];
                    fx -= rintf(fx); fy -= rintf(fy); fz -= rintf(fz);
                    float rx = fx*c0 + fy*c3 + fz*c6;
                    float ry = fx*c1 + fy*c4 + fz*c7;
                    float rz = fx*c2 + fy*c5 + fz*c8;
                    float r2 = fmaf(rx, rx, fmaf(ry, ry, rz * rz));
                    float rinv = __builtin_amdgcn_rsqf(r2);
                    float val = p.w * rinv * erfc_a(r2 * rinv, r2);
                    acc2 += (v2 && j < i2) ? val : 0.0f;
                }
            }
            float acc_e = acc1 * q1 + acc2 * q2;
            float s = block_reduce(acc_e);
            if (tid == 0) rpart[rbid] = s;
        }
    }
}

// Single-block finalize: chunk partials -> |S(k)|^2 (x2 for +-k) with coeff,
// plus self-energy, plus real-space block partials. Plain store to e_out.
__global__ __launch_bounds__(256) void finalize_kernel(const float* __restrict__ spart,
                                                       const float* __restrict__ rpart,
                                                       const float* __restrict__ q,
                                                       const float* __restrict__ cell,
                                                       float* __restrict__ e_out,
                                                       int N, int nb_real) {
    float inv[9]; float det;
    invert3x3(cell, inv, &det);
    float vol = fabsf(det);
    float pref = 2.0f * (TWO_PI / vol);   // x2: +-k symmetry
    int tid = threadIdx.x;

    float acc = 0.0f;
    for (int t = tid; t < NK_HALF; t += 256) {
        float sr = 0.0f, si = 0.0f;
        #pragma unroll
        for (int c = 0; c < RECIP_CHUNKS; ++c) {
            sr += spart[(size_t)(c*2    ) * KPAD + t];
            si += spart[(size_t)(c*2 + 1) * KPAD + t];
        }
        float nx = (float)(t / KD2 - KMAX);
        float ny = (float)((t / KDIM) % KDIM - KMAX);
        float nz = (float)(t % KDIM - KMAX);
        float kvx = TWO_PI * (nx*inv[0] + ny*inv[1] + nz*inv[2]);
        float kvy = TWO_PI * (nx*inv[3] + ny*inv[4] + nz*inv[5]);
        float kvz = TWO_PI * (nx*inv[6] + ny*inv[7] + nz*inv[8]);
        float k2 = fmaf(kvx, kvx, fmaf(kvy, kvy, kvz * kvz));
        float coeff = __expf(-k2 * INV_4A2) / k2;
        acc = fmaf(pref * coeff, fmaf(sr, sr, si * si), acc);
    }
    for (int t = tid; t < N; t += 256) {
        float qt = q[t];
        acc = fmaf(SELF_COEF * qt, qt, acc);
    }
    for (int t = tid; t < nb_real; t += 256) {
        acc += rpart[t];
    }
    float s = block_reduce(acc);
    if (tid == 0) e_out[0] = s;
}

extern "C" void kernel_launch(void* const* d_in, const int* in_sizes, int n_in,
                              void* d_out, int out_size, void* d_ws, size_t ws_size,
                              hipStream_t stream) {
    const float* pos  = (const float*)d_in[0];
    const float* q    = (const float*)d_in[1];
    const float* cell = (const float*)d_in[2];
    int N = in_sizes[1];
    float* e_out = (float*)d_out;

    float* spart = (float*)d_ws;                          // RECIP_CHUNKS*2*KPAD floats
    float* rpart = spart + (size_t)RECIP_CHUNKS*2*KPAD;   // nb_real floats

    // real-space triangular block count (ITILE=512)
    int nbi = (N + ITILE - 1) / ITILE;
    int nb_real = 0;
    for (int bi = 0; bi < nbi; ++bi) {
        int up = (N < (bi + 1) * ITILE) ? N : (bi + 1) * ITILE;
        nb_real += (up + JTILE - 1) / JTILE;
    }
    int nb_recip = RECIP_KB * RECIP_CHUNKS;   // 160

    fused_kernel<<<nb_recip + nb_real, 256, 0, stream>>>(pos, q, cell, spart, rpart, N, nb_recip);

    finalize_kernel<<<1, 256, 0, stream>>>(spart, rpart, q, cell, e_out, N, nb_real);
}